// Round 2
// baseline (1086.666 us; speedup 1.0000x reference)
//
#include <hip/hip_runtime.h>
#include <hip/hip_bf16.h>
#include <cstdint>
#include <cstddef>

#define S_ 2048
#define D_ 1024
#define H_ 16
#define DK_ 64
#define B_ 2

typedef unsigned short u16;
typedef __attribute__((ext_vector_type(8))) short bf16x8;
typedef __attribute__((ext_vector_type(4))) float f32x4;

__device__ inline u16 f2bf(float f) {
    union { float f; unsigned u; } c; c.f = f;
    unsigned u = c.u;
    unsigned r = (u + 0x7fffu + ((u >> 16) & 1u)) >> 16;
    return (u16)r;
}

// load 8 fp32, round to bf16, pack into uint4 (16B)
__device__ inline uint4 cvt8(const float* __restrict__ src) {
    float4 f0 = *(const float4*)(src);
    float4 f1 = *(const float4*)(src + 4);
    union { u16 h[8]; uint4 v; } u;
    u.h[0] = f2bf(f0.x); u.h[1] = f2bf(f0.y); u.h[2] = f2bf(f0.z); u.h[3] = f2bf(f0.w);
    u.h[4] = f2bf(f1.x); u.h[5] = f2bf(f1.y); u.h[6] = f2bf(f1.z); u.h[7] = f2bf(f1.w);
    return u.v;
}

// C = A(MxK) * B(NxK)^T + bias, fp32 accumulate, bf16 MFMA.
// AF32/BF32: global operand is fp32 (convert during staging) vs bf16.
// CF32: output fp32 vs bf16.
// MODE 0: C[row*N+col]                     (plain row-major)
// MODE 1: head-split (B,H,S,DK)            (Q/K projections)
// MODE 2: head-split transposed (B,H,DK,S) (V projection)
// MODE 3: ctx->concat, per-bh GEMM (blockIdx.z = bh), A/B offset by bh
template<int BM, int BN, int MODE, bool CAUSAL, bool AF32, bool BF32, bool CF32>
__global__ void __launch_bounds__(256)
gemm_bt(const void* __restrict__ Av, const void* __restrict__ Bv,
        const float* __restrict__ bias, void* __restrict__ Cv,
        int M, int N, int K, int lda, int ldb)
{
    constexpr int BK = 32;
    constexpr int WN = BN / 64;   // waves along N
    constexpr int WM = 4 / WN;    // waves along M (wave tile = 64x64)
    static_assert(BM == WM * 64, "tile/wave mismatch");

    __shared__ __align__(16) u16 As[BM * BK];
    __shared__ __align__(16) u16 Bs[BN * BK];

    const int tid  = threadIdx.x;
    const int lane = tid & 63;
    const int wave = tid >> 6;
    const int wm = wave / WN;
    const int wn = wave % WN;
    const int m0 = blockIdx.y * BM;
    const int n0 = blockIdx.x * BN;
    const int bh = blockIdx.z;

    const float* Af = (const float*)Av;
    const u16*   Ab = (const u16*)Av;
    const float* Bf = (const float*)Bv;
    const u16*   Bb = (const u16*)Bv;
    if (MODE == 3) {
        size_t ao = (size_t)bh * S_ * S_;
        size_t bo = (size_t)bh * DK_ * S_;
        Af += ao; Ab += ao; Bf += bo; Bb += bo;
    }

    int Keff = K;
    if (CAUSAL) { int ke = m0 + BM; Keff = (ke < K) ? ke : K; }

    f32x4 acc[4][4];
#pragma unroll
    for (int i = 0; i < 4; ++i)
#pragma unroll
        for (int j = 0; j < 4; ++j)
            acc[i][j] = (f32x4){0.f, 0.f, 0.f, 0.f};

    const int fr = lane & 15;
    const int fk = (lane >> 4) << 3;

    for (int k0 = 0; k0 < Keff; k0 += BK) {
#pragma unroll
        for (int i = 0; i < BM / 64; ++i) {
            int linear = i * 256 + tid;
            int row = linear >> 2;
            int kk  = (linear & 3) << 3;
            size_t off = (size_t)(m0 + row) * lda + k0 + kk;
            *(uint4*)&As[linear << 3] =
                AF32 ? cvt8(&Af[off]) : *(const uint4*)&Ab[off];
        }
#pragma unroll
        for (int i = 0; i < BN / 64; ++i) {
            int linear = i * 256 + tid;
            int row = linear >> 2;
            int kk  = (linear & 3) << 3;
            size_t off = (size_t)(n0 + row) * ldb + k0 + kk;
            *(uint4*)&Bs[linear << 3] =
                BF32 ? cvt8(&Bf[off]) : *(const uint4*)&Bb[off];
        }
        __syncthreads();

        bf16x8 af[4], bfv[4];
#pragma unroll
        for (int mt = 0; mt < 4; ++mt)
            af[mt] = *(const bf16x8*)&As[(wm * 64 + mt * 16 + fr) * BK + fk];
#pragma unroll
        for (int nt = 0; nt < 4; ++nt)
            bfv[nt] = *(const bf16x8*)&Bs[(wn * 64 + nt * 16 + fr) * BK + fk];
#pragma unroll
        for (int mt = 0; mt < 4; ++mt)
#pragma unroll
            for (int nt = 0; nt < 4; ++nt)
                acc[mt][nt] = __builtin_amdgcn_mfma_f32_16x16x32_bf16(
                    af[mt], bfv[nt], acc[mt][nt], 0, 0, 0);
        __syncthreads();
    }

#pragma unroll
    for (int mt = 0; mt < 4; ++mt) {
#pragma unroll
        for (int nt = 0; nt < 4; ++nt) {
#pragma unroll
            for (int r = 0; r < 4; ++r) {
                int row = m0 + wm * 64 + mt * 16 + ((lane >> 4) << 2) + r;
                int col = n0 + wn * 64 + nt * 16 + (lane & 15);
                float v = acc[mt][nt][r];
                if (bias) v += bias[col];
                size_t addr;
                if (MODE == 0) {
                    addr = (size_t)row * N + col;
                } else if (MODE == 1) {
                    addr = ((size_t)(row >> 11) << 21) + ((size_t)(col >> 6) << 17)
                         + ((size_t)(row & 2047) << 6) + (size_t)(col & 63);
                } else if (MODE == 2) {
                    addr = ((size_t)(row >> 11) << 21) + ((size_t)(col >> 6) << 17)
                         + ((size_t)(col & 63) << 11) + (size_t)(row & 2047);
                } else {
                    addr = (size_t)(bh >> 4) * S_ * D_ + (size_t)(bh & 15) * DK_
                         + (size_t)row * D_ + (size_t)col;
                }
                if (CF32) ((float*)Cv)[addr] = v;
                else      ((u16*)Cv)[addr]   = f2bf(v);
            }
        }
    }
}

// Per (q-tile, bh): row sums of exp(scores) over k <= q  ->  sums (fp32)
__global__ void __launch_bounds__(256)
attn_sums(const u16* __restrict__ Qh, const u16* __restrict__ Kh,
          float* __restrict__ sums)
{
    __shared__ __align__(16) u16 Qs[128 * 64];
    __shared__ __align__(16) u16 Ks[128 * 64];
    __shared__ float rowsum[128];

    const int tid  = threadIdx.x;
    const int lane = tid & 63;
    const int wave = tid >> 6;
    const int wm = wave >> 1, wn = wave & 1;
    const int qt = blockIdx.x;
    const int bh = blockIdx.y;

    const u16* Qbase = Qh + (size_t)bh * S_ * DK_ + (size_t)qt * 128 * DK_;
    const u16* Kbase = Kh + (size_t)bh * S_ * DK_;

#pragma unroll
    for (int i = 0; i < 4; ++i) {
        int linear = i * 256 + tid;
        *(uint4*)&Qs[linear << 3] = *(const uint4*)&Qbase[(size_t)linear << 3];
    }
    if (tid < 128) rowsum[tid] = 0.f;

    float rs[4][4];
#pragma unroll
    for (int i = 0; i < 4; ++i)
#pragma unroll
        for (int j = 0; j < 4; ++j) rs[i][j] = 0.f;

    const int fr = lane & 15;
    const int fq = lane >> 4;

    for (int kt = 0; kt <= qt; ++kt) {
        __syncthreads();
#pragma unroll
        for (int i = 0; i < 4; ++i) {
            int linear = i * 256 + tid;
            *(uint4*)&Ks[linear << 3] =
                *(const uint4*)&Kbase[(size_t)kt * 128 * DK_ + (linear << 3)];
        }
        __syncthreads();

        f32x4 acc[4][4];
#pragma unroll
        for (int i = 0; i < 4; ++i)
#pragma unroll
            for (int j = 0; j < 4; ++j) acc[i][j] = (f32x4){0.f, 0.f, 0.f, 0.f};

#pragma unroll
        for (int ks = 0; ks < 64; ks += 32) {
            bf16x8 af[4], bfv[4];
#pragma unroll
            for (int mt = 0; mt < 4; ++mt)
                af[mt] = *(const bf16x8*)&Qs[(wm * 64 + mt * 16 + fr) * DK_ + ks + (fq << 3)];
#pragma unroll
            for (int nt = 0; nt < 4; ++nt)
                bfv[nt] = *(const bf16x8*)&Ks[(wn * 64 + nt * 16 + fr) * DK_ + ks + (fq << 3)];
#pragma unroll
            for (int mt = 0; mt < 4; ++mt)
#pragma unroll
                for (int nt = 0; nt < 4; ++nt)
                    acc[mt][nt] = __builtin_amdgcn_mfma_f32_16x16x32_bf16(
                        af[mt], bfv[nt], acc[mt][nt], 0, 0, 0);
        }

        const bool diag = (kt == qt);
#pragma unroll
        for (int mt = 0; mt < 4; ++mt)
#pragma unroll
            for (int nt = 0; nt < 4; ++nt)
#pragma unroll
                for (int r = 0; r < 4; ++r) {
                    int row = wm * 64 + mt * 16 + (fq << 2) + r;
                    int col = wn * 64 + nt * 16 + fr;
                    if (!diag || col <= row)
                        rs[mt][r] += __expf(acc[mt][nt][r] * 0.125f);
                }
    }

#pragma unroll
    for (int mt = 0; mt < 4; ++mt)
#pragma unroll
        for (int r = 0; r < 4; ++r) {
            float v = rs[mt][r];
            v += __shfl_xor(v, 1, 64);
            v += __shfl_xor(v, 2, 64);
            v += __shfl_xor(v, 4, 64);
            v += __shfl_xor(v, 8, 64);
            rs[mt][r] = v;
        }
    __syncthreads();
    if (fr == 0) {
#pragma unroll
        for (int mt = 0; mt < 4; ++mt)
#pragma unroll
            for (int r = 0; r < 4; ++r)
                atomicAdd(&rowsum[wm * 64 + mt * 16 + (fq << 2) + r], rs[mt][r]);
    }
    __syncthreads();
    if (tid < 128)
        sums[(size_t)bh * S_ + (size_t)qt * 128 + tid] = rowsum[tid];
}

// Per (k-tile, q-tile, bh): write normalized attn tile (fp32; zeros above diagonal)
__global__ void __launch_bounds__(256)
attn_write(const u16* __restrict__ Qh, const u16* __restrict__ Kh,
           const float* __restrict__ sums, float* __restrict__ attn)
{
    const int kt = blockIdx.x, qt = blockIdx.y, bh = blockIdx.z;
    const int tid = threadIdx.x;
    float* out = attn + (size_t)bh * S_ * S_;

    if (kt > qt) {
        float4 z = {0.f, 0.f, 0.f, 0.f};
#pragma unroll
        for (int i = 0; i < 16; ++i) {
            int linear = i * 256 + tid;
            int row = linear >> 5;
            int c   = (linear & 31) << 2;
            *(float4*)&out[(size_t)(qt * 128 + row) * S_ + kt * 128 + c] = z;
        }
        return;
    }

    __shared__ __align__(16) u16 Qs[128 * 64];
    __shared__ __align__(16) u16 Ks[128 * 64];

    const int lane = tid & 63;
    const int wave = tid >> 6;
    const int wm = wave >> 1, wn = wave & 1;

    const u16* Qbase = Qh + (size_t)bh * S_ * DK_ + (size_t)qt * 128 * DK_;
    const u16* Kbase = Kh + (size_t)bh * S_ * DK_ + (size_t)kt * 128 * DK_;

#pragma unroll
    for (int i = 0; i < 4; ++i) {
        int linear = i * 256 + tid;
        *(uint4*)&Qs[linear << 3] = *(const uint4*)&Qbase[linear << 3];
        *(uint4*)&Ks[linear << 3] = *(const uint4*)&Kbase[linear << 3];
    }
    __syncthreads();

    f32x4 acc[4][4];
#pragma unroll
    for (int i = 0; i < 4; ++i)
#pragma unroll
        for (int j = 0; j < 4; ++j) acc[i][j] = (f32x4){0.f, 0.f, 0.f, 0.f};

    const int fr = lane & 15;
    const int fq = lane >> 4;

#pragma unroll
    for (int ks = 0; ks < 64; ks += 32) {
        bf16x8 af[4], bfv[4];
#pragma unroll
        for (int mt = 0; mt < 4; ++mt)
            af[mt] = *(const bf16x8*)&Qs[(wm * 64 + mt * 16 + fr) * DK_ + ks + (fq << 3)];
#pragma unroll
        for (int nt = 0; nt < 4; ++nt)
            bfv[nt] = *(const bf16x8*)&Ks[(wn * 64 + nt * 16 + fr) * DK_ + ks + (fq << 3)];
#pragma unroll
        for (int mt = 0; mt < 4; ++mt)
#pragma unroll
            for (int nt = 0; nt < 4; ++nt)
                acc[mt][nt] = __builtin_amdgcn_mfma_f32_16x16x32_bf16(
                    af[mt], bfv[nt], acc[mt][nt], 0, 0, 0);
    }

    const bool diag = (kt == qt);
#pragma unroll
    for (int mt = 0; mt < 4; ++mt)
#pragma unroll
        for (int nt = 0; nt < 4; ++nt)
#pragma unroll
            for (int r = 0; r < 4; ++r) {
                int row = wm * 64 + mt * 16 + (fq << 2) + r;
                int col = wn * 64 + nt * 16 + fr;
                int grow = qt * 128 + row;
                float p = 0.f;
                if (!diag || col <= row)
                    p = __expf(acc[mt][nt][r] * 0.125f)
                        / sums[(size_t)bh * S_ + grow];
                out[(size_t)grow * S_ + (size_t)(kt * 128 + col)] = p;
            }
}

extern "C" void kernel_launch(void* const* d_in, const int* in_sizes, int n_in,
                              void* d_out, int out_size, void* d_ws, size_t ws_size,
                              hipStream_t stream)
{
    const float* Q  = (const float*)d_in[0];
    const float* K  = (const float*)d_in[1];
    const float* V  = (const float*)d_in[2];
    // d_in[3] = mask (int32 causal tril) — causal structure applied analytically
    const float* WQ = (const float*)d_in[4];
    const float* bQ = (const float*)d_in[5];
    const float* WK = (const float*)d_in[6];
    const float* bK = (const float*)d_in[7];
    const float* WV = (const float*)d_in[8];
    const float* bV = (const float*)d_in[9];
    const float* WO = (const float*)d_in[10];
    const float* bO = (const float*)d_in[11];

    float* outF  = (float*)d_out;
    float* attnF = outF + (size_t)B_ * S_ * D_;

    u16* Qh = (u16*)d_ws;
    u16* Kh = Qh + (size_t)B_ * S_ * D_;
    u16* Vt = Kh + (size_t)B_ * S_ * D_;
    u16* Cc = Vt + (size_t)B_ * S_ * D_;
    float* sums = (float*)(Cc + (size_t)B_ * S_ * D_);

    dim3 blk(256, 1, 1);
    const int M = B_ * S_;  // 4096

    // Projections (fp32 in -> bf16 head-split out)
    gemm_bt<128, 128, 1, false, true, true, false>
        <<<dim3(D_ / 128, M / 128, 1), blk, 0, stream>>>(
        Q, WQ, bQ, Qh, M, D_, D_, D_, D_);
    gemm_bt<128, 128, 1, false, true, true, false>
        <<<dim3(D_ / 128, M / 128, 1), blk, 0, stream>>>(
        K, WK, bK, Kh, M, D_, D_, D_, D_);
    gemm_bt<128, 128, 2, false, true, true, false>
        <<<dim3(D_ / 128, M / 128, 1), blk, 0, stream>>>(
        V, WV, bV, Vt, M, D_, D_, D_, D_);

    // Softmax denominators
    attn_sums<<<dim3(S_ / 128, B_ * H_, 1), blk, 0, stream>>>(Qh, Kh, sums);

    // Normalized attention matrix -> d_out (second output, fp32)
    attn_write<<<dim3(S_ / 128, S_ / 128, B_ * H_), blk, 0, stream>>>(
        Qh, Kh, sums, attnF);

    // ctx = attn @ V (per-bh GEMM, causal K truncation), concat layout, bf16 out
    gemm_bt<256, 64, 3, true, true, false, false>
        <<<dim3(1, S_ / 256, B_ * H_), blk, 0, stream>>>(
        attnF, Vt, nullptr, Cc, S_, DK_, S_, S_, S_);

    // out = concat @ WO^T + bO -> d_out (first output, fp32)
    gemm_bt<128, 128, 0, false, false, true, true>
        <<<dim3(D_ / 128, M / 128, 1), blk, 0, stream>>>(
        Cc, WO, bO, outF, M, D_, D_, D_, D_);
}